// Round 1
// baseline (66.394 us; speedup 1.0000x reference)
//
#include <hip/hip_runtime.h>
#include <hip/hip_bf16.h>

// Problem constants (reference: N,E,H,L = 64,64,768,512; eps=1e-12)
#define Nn 64
#define Ee 64
#define Hh 768
#define Ll 512
#define NEH (Nn * Ee * Hh) // 3145728 state elems
#define NEL (Nn * Ee * Ll) // 2097152 mapping elems

typedef __attribute__((ext_vector_type(8))) short bf16x8; // 8 bf16 = 4 VGPRs (MFMA A/B frag)
typedef __attribute__((ext_vector_type(4))) float f32x4;  // MFMA C/D frag

// ---------------------------------------------------------------------------
// Pre-pass: fp32 -> bf16 convert + transpose to K-major layouts in workspace.
//   sT[n][h][e]  (H x E per n)   mT[n][l][e]  (L x E per n)
// Reads are fully coalesced (innermost dim contiguous); writes are scattered
// 2B stride-128B but total only 10.5 MB (L2 write-combines full lines).
// ---------------------------------------------------------------------------
__global__ __launch_bounds__(256) void cvt_transpose(
    const float* __restrict__ state, const float* __restrict__ mapping,
    __hip_bfloat16* __restrict__ sT, __hip_bfloat16* __restrict__ mT)
{
    int idx = blockIdx.x * 256 + threadIdx.x;
    if (idx < NEH) {
        int h  = idx % Hh;
        int ne = idx / Hh;
        int e  = ne % Ee;
        int n  = ne / Ee;
        sT[(n * Hh + h) * Ee + e] = __float2bfloat16(state[idx]);
    } else {
        int j  = idx - NEH;
        int l  = j % Ll;
        int ne = j / Ll;
        int e  = ne % Ee;
        int n  = ne / Ee;
        mT[(n * Ll + l) * Ee + e] = __float2bfloat16(mapping[j]);
    }
}

// ---------------------------------------------------------------------------
// Fused GEMM (C = mapping^T @ state, per n) + LayerNorm over H.
// Grid: one block per (n, 16-row l-tile) -> 64*32 = 2048 blocks, 256 threads.
// Each of 4 waves owns 12 h-tiles of 16x16 (wave w covers h in [w*192,(w+1)*192)).
// K = E = 64 -> 2 x mfma_f32_16x16x32_bf16 per tile.
// Both operands staged K-major, so each fragment is ONE 16B contiguous load.
// C/D layout (HW-verified): D[row][col], row=(lane>>4)*4+reg, col=lane&15.
//   row -> l (tile row), col -> h.
// ---------------------------------------------------------------------------
__global__ __launch_bounds__(256) void gemm_ln(
    const __hip_bfloat16* __restrict__ sT, // [N][H][E]
    const __hip_bfloat16* __restrict__ mT, // [N][L][E]
    const float* __restrict__ gamma,
    const float* __restrict__ beta,
    float* __restrict__ out)               // [N][L][H]
{
    const int bid  = blockIdx.x;
    const int n    = bid >> 5;        // 32 l-tiles per n
    const int l0   = (bid & 31) << 4; // 16 rows per tile
    const int tid  = threadIdx.x;
    const int w    = tid >> 6;        // wave 0..3
    const int lane = tid & 63;
    const int g    = lane >> 4;       // k-group 0..3
    const int c    = lane & 15;       // col index (h within tile / row within A)

    // A fragments: mT[n][l0+c][k], k = kk*32 + 8*g + j  (8 contiguous bf16)
    const __hip_bfloat16* Arow = mT + (n * Ll + l0 + c) * Ee + g * 8;
    const bf16x8 a0 = *reinterpret_cast<const bf16x8*>(Arow);
    const bf16x8 a1 = *reinterpret_cast<const bf16x8*>(Arow + 32);

    // B fragments base: sT[n][h][k], h = w*192 + t*16 + c
    const __hip_bfloat16* Bbase = sT + (n * Hh + w * 192 + c) * Ee + g * 8;

    f32x4 acc[12];
#pragma unroll
    for (int t = 0; t < 12; ++t) acc[t] = (f32x4){0.f, 0.f, 0.f, 0.f};

#pragma unroll
    for (int t = 0; t < 12; ++t) {
        const __hip_bfloat16* bp = Bbase + t * 16 * Ee;
        bf16x8 b0 = *reinterpret_cast<const bf16x8*>(bp);
        bf16x8 b1 = *reinterpret_cast<const bf16x8*>(bp + 32);
        acc[t] = __builtin_amdgcn_mfma_f32_16x16x32_bf16(a0, b0, acc[t], 0, 0, 0);
        acc[t] = __builtin_amdgcn_mfma_f32_16x16x32_bf16(a1, b1, acc[t], 0, 0, 0);
    }

    // ---------------- LayerNorm over H=768 ----------------
    // Lane holds rows li = 4*g + r (r=0..3), cols h = w*192 + t*16 + c.
    float s[4], q[4];
#pragma unroll
    for (int r = 0; r < 4; ++r) { s[r] = 0.f; q[r] = 0.f; }
#pragma unroll
    for (int t = 0; t < 12; ++t) {
#pragma unroll
        for (int r = 0; r < 4; ++r) {
            float v = acc[t][r];
            s[r] += v;
            q[r] += v * v;
        }
    }
    // Reduce across the 16 lanes (c dim) of each k-group.
#pragma unroll
    for (int off = 1; off < 16; off <<= 1) {
#pragma unroll
        for (int r = 0; r < 4; ++r) {
            s[r] += __shfl_xor(s[r], off, 64);
            q[r] += __shfl_xor(q[r], off, 64);
        }
    }
    // Cross-wave combine (each wave has a 192-col partial for every row).
    __shared__ float redS[16][4];
    __shared__ float redQ[16][4];
    if (c == 0) {
#pragma unroll
        for (int r = 0; r < 4; ++r) {
            redS[g * 4 + r][w] = s[r];
            redQ[g * 4 + r][w] = q[r];
        }
    }
    __syncthreads();

    float mu[4], rstd[4];
#pragma unroll
    for (int r = 0; r < 4; ++r) {
        int li = g * 4 + r;
        float S = redS[li][0] + redS[li][1] + redS[li][2] + redS[li][3];
        float Q = redQ[li][0] + redQ[li][1] + redQ[li][2] + redQ[li][3];
        float m = S * (1.f / Hh);
        float v = Q * (1.f / Hh) - m * m;
        mu[r]   = m;
        rstd[r] = rsqrtf(v + 1e-12f);
    }

    // ---------------- Epilogue: normalize + gamma/beta + store ----------------
    float* outn = out + ((size_t)(n * Ll + l0)) * Hh;
#pragma unroll
    for (int t = 0; t < 12; ++t) {
        int h = w * 192 + t * 16 + c;
        float gm = gamma[h];
        float bt = beta[h];
#pragma unroll
        for (int r = 0; r < 4; ++r) {
            int li = g * 4 + r;
            outn[li * Hh + h] = (acc[t][r] - mu[r]) * rstd[r] * gm + bt;
        }
    }
}

extern "C" void kernel_launch(void* const* d_in, const int* in_sizes, int n_in,
                              void* d_out, int out_size, void* d_ws, size_t ws_size,
                              hipStream_t stream)
{
    const float* state   = (const float*)d_in[0]; // (N,E,H)
    const float* mapping = (const float*)d_in[1]; // (N,E,L)
    const float* gamma   = (const float*)d_in[2]; // (H,)
    const float* beta    = (const float*)d_in[3]; // (H,)
    float* out           = (float*)d_out;         // (N,L,H)

    __hip_bfloat16* sT = (__hip_bfloat16*)d_ws;   // N*H*E bf16
    __hip_bfloat16* mT = sT + NEH;                // N*L*E bf16  (total ws use: 10.5 MB)

    cvt_transpose<<<(NEH + NEL) / 256, 256, 0, stream>>>(state, mapping, sT, mT);
    gemm_ln<<<Nn * (Ll / 16), 256, 0, stream>>>(sT, mT, gamma, beta, out);
}

// Round 2
// 42.823 us; speedup vs baseline: 1.5504x; 1.5504x over previous
//
#include <hip/hip_runtime.h>
#include <hip/hip_bf16.h>

// Problem constants (reference: N,E,H,L = 64,64,768,512; eps=1e-12)
#define Nn 64
#define Ee 64
#define Hh 768
#define Ll 512
#define NEH (Nn * Ee * Hh) // 3145728 state elems
#define NEL (Nn * Ee * Ll) // 2097152 mapping elems

typedef __attribute__((ext_vector_type(8))) short bf16x8; // 8 bf16 = 4 VGPRs (MFMA A/B frag)
typedef __attribute__((ext_vector_type(4))) float f32x4;  // MFMA C/D frag

// ---------------------------------------------------------------------------
// Pre-pass: fp32 -> bf16 convert + transpose, LDS-tiled so BOTH the global
// read and the global write are fully coalesced (R1's 2B-stride-128B scatter
// writes were the dominant cost: partial-line HBM RMW).
//   sT[n][h][e]  (H x E per n)   mT[n][l][e]  (L x E per n)
// One block per 64(e) x 64(x) tile. 768 state tiles + 512 mapping tiles.
// ---------------------------------------------------------------------------
__global__ __launch_bounds__(256) void cvt_transpose(
    const float* __restrict__ state, const float* __restrict__ mapping,
    __hip_bfloat16* __restrict__ sT, __hip_bfloat16* __restrict__ mT)
{
    __shared__ unsigned short lds[64][66]; // [x][e], stride 132B: 4B-aligned rows, bank-spread

    int b = blockIdx.x;
    const float* src;
    __hip_bfloat16* dst;
    int W, x0;
    if (b < Nn * (Hh / 64)) {            // state tiles
        int n = b / (Hh / 64);
        x0 = (b % (Hh / 64)) * 64;
        src = state + (size_t)n * Ee * Hh;
        dst = sT + (size_t)n * Hh * Ee;
        W = Hh;
    } else {                              // mapping tiles
        b -= Nn * (Hh / 64);
        int n = b / (Ll / 64);
        x0 = (b % (Ll / 64)) * 64;
        src = mapping + (size_t)n * Ee * Ll;
        dst = mT + (size_t)n * Ll * Ee;
        W = Ll;
    }

    // Read phase: wave reads one e-row of 64 consecutive floats (256B) per iter.
    const int tx = threadIdx.x & 63;
    const int tq = threadIdx.x >> 6;
#pragma unroll
    for (int i = 0; i < 16; ++i) {
        int e = tq * 16 + i;
        float v = src[(size_t)e * W + x0 + tx];
        union { __hip_bfloat16 b16; unsigned short u; } cv;
        cv.b16 = __float2bfloat16(v);
        lds[tx][e] = cv.u;
    }
    __syncthreads();

    // Write phase: lane packs 2 bf16 -> one 4B store; half-wave writes a full
    // 128B row of dst (64 e contiguous). 256B per wave-instruction.
    const int e2 = (threadIdx.x & 31) * 2;
    const int xq = threadIdx.x >> 5;
#pragma unroll
    for (int i = 0; i < 8; ++i) {
        int x = xq * 8 + i;
        unsigned int v = *reinterpret_cast<const unsigned int*>(&lds[x][e2]);
        *reinterpret_cast<unsigned int*>(
            reinterpret_cast<unsigned short*>(dst) + (size_t)(x0 + x) * Ee + e2) = v;
    }
}

// ---------------------------------------------------------------------------
// Fused GEMM (out[n,l,h] = sum_e mapping[n,e,l]*state[n,e,h]) + LayerNorm(H).
//
// Operand roles SWAPPED vs R1: A = state fragment (M-rows = h), B = mapping
// fragment (N-cols = l). D[row=h][col=l] with row=(lane>>4)*4+reg means each
// lane's f32x4 acc is 4 CONSECUTIVE h values -> direct float4 stores
// (1 KB/wave-instr; R1's scalar stores were 256B/instr).
//
// Grid: one block per (n, 32-row l-tile) -> 64*16 = 1024 blocks, 256 threads.
// Wave w owns h in [w*192,(w+1)*192) (12 16-h tiles), all 32 l rows
// (2 sub-tiles u). B-frags are loaded once and register-resident.
// ---------------------------------------------------------------------------
__global__ __launch_bounds__(256) void gemm_ln(
    const __hip_bfloat16* __restrict__ sT, // [N][H][E]
    const __hip_bfloat16* __restrict__ mT, // [N][L][E]
    const float* __restrict__ gamma,
    const float* __restrict__ beta,
    float* __restrict__ out)               // [N][L][H]
{
    const int bid  = blockIdx.x;
    const int n    = bid >> 4;        // 16 l-tiles per n
    const int l0   = (bid & 15) << 5; // 32 rows per tile
    const int tid  = threadIdx.x;
    const int w    = tid >> 6;        // wave 0..3
    const int lane = tid & 63;
    const int g    = lane >> 4;       // k-group 0..3 (also h sub-offset in D)
    const int c    = lane & 15;       // operand row index (h for A, l for B)

    // B fragments (mapping rows l0+u*16+c), k = 8*g + j and +32
    bf16x8 b0[2], b1[2];
#pragma unroll
    for (int u = 0; u < 2; ++u) {
        const __hip_bfloat16* Brow = mT + (size_t)(n * Ll + l0 + u * 16 + c) * Ee + g * 8;
        b0[u] = *reinterpret_cast<const bf16x8*>(Brow);
        b1[u] = *reinterpret_cast<const bf16x8*>(Brow + 32);
    }

    f32x4 acc[12][2];
#pragma unroll
    for (int t = 0; t < 12; ++t)
#pragma unroll
        for (int u = 0; u < 2; ++u) acc[t][u] = (f32x4){0.f, 0.f, 0.f, 0.f};

    const __hip_bfloat16* Abase = sT + (size_t)(n * Hh + w * 192 + c) * Ee + g * 8;
#pragma unroll
    for (int t = 0; t < 12; ++t) {
        const __hip_bfloat16* ap = Abase + (size_t)t * 16 * Ee;
        bf16x8 a0 = *reinterpret_cast<const bf16x8*>(ap);
        bf16x8 a1 = *reinterpret_cast<const bf16x8*>(ap + 32);
#pragma unroll
        for (int u = 0; u < 2; ++u) {
            acc[t][u] = __builtin_amdgcn_mfma_f32_16x16x32_bf16(a0, b0[u], acc[t][u], 0, 0, 0);
            acc[t][u] = __builtin_amdgcn_mfma_f32_16x16x32_bf16(a1, b1[u], acc[t][u], 0, 0, 0);
        }
    }

    // ---------------- LayerNorm over H=768 ----------------
    // Lane holds l rows (l0+u*16+c) and h values {w*192 + t*16 + g*4 + r}.
    float s[2] = {0.f, 0.f}, q[2] = {0.f, 0.f};
#pragma unroll
    for (int t = 0; t < 12; ++t)
#pragma unroll
        for (int u = 0; u < 2; ++u)
#pragma unroll
            for (int r = 0; r < 4; ++r) {
                float v = acc[t][u][r];
                s[u] += v;
                q[u] += v * v;
            }
    // Sum over g (lanes c, c+16, c+32, c+48): two butterfly steps.
#pragma unroll
    for (int off = 16; off < 64; off <<= 1)
#pragma unroll
        for (int u = 0; u < 2; ++u) {
            s[u] += __shfl_xor(s[u], off, 64);
            q[u] += __shfl_xor(q[u], off, 64);
        }
    // Cross-wave combine: each wave has the partial over its 192-h slice.
    __shared__ float redS[32][4];
    __shared__ float redQ[32][4];
    if (g == 0) {
#pragma unroll
        for (int u = 0; u < 2; ++u) {
            redS[u * 16 + c][w] = s[u];
            redQ[u * 16 + c][w] = q[u];
        }
    }
    __syncthreads();

    float mu[2], rstd[2];
#pragma unroll
    for (int u = 0; u < 2; ++u) {
        int li = u * 16 + c;
        float S = redS[li][0] + redS[li][1] + redS[li][2] + redS[li][3];
        float Q = redQ[li][0] + redQ[li][1] + redQ[li][2] + redQ[li][3];
        float m = S * (1.f / Hh);
        float v = Q * (1.f / Hh) - m * m;
        mu[u]   = m;
        rstd[u] = rsqrtf(v + 1e-12f);
    }

    // ---------------- Epilogue: normalize + gamma/beta + float4 stores ----------------
#pragma unroll
    for (int t = 0; t < 12; ++t) {
        int hb = w * 192 + t * 16 + g * 4;
        f32x4 gm = *reinterpret_cast<const f32x4*>(gamma + hb);
        f32x4 bt = *reinterpret_cast<const f32x4*>(beta + hb);
#pragma unroll
        for (int u = 0; u < 2; ++u) {
            f32x4 v;
#pragma unroll
            for (int r = 0; r < 4; ++r)
                v[r] = (acc[t][u][r] - mu[u]) * rstd[u] * gm[r] + bt[r];
            *reinterpret_cast<f32x4*>(
                out + (size_t)(n * Ll + l0 + u * 16 + c) * Hh + hb) = v;
        }
    }
}

extern "C" void kernel_launch(void* const* d_in, const int* in_sizes, int n_in,
                              void* d_out, int out_size, void* d_ws, size_t ws_size,
                              hipStream_t stream)
{
    const float* state   = (const float*)d_in[0]; // (N,E,H)
    const float* mapping = (const float*)d_in[1]; // (N,E,L)
    const float* gamma   = (const float*)d_in[2]; // (H,)
    const float* beta    = (const float*)d_in[3]; // (H,)
    float* out           = (float*)d_out;         // (N,L,H)

    __hip_bfloat16* sT = (__hip_bfloat16*)d_ws;   // N*H*E bf16
    __hip_bfloat16* mT = sT + NEH;                // N*L*E bf16  (total ws use: 10.5 MB)

    const int tiles = Nn * (Hh / 64) + Nn * (Ll / 64); // 768 + 512 = 1280
    cvt_transpose<<<tiles, 256, 0, stream>>>(state, mapping, sT, mT);
    gemm_ln<<<Nn * (Ll / 32), 256, 0, stream>>>(sT, mT, gamma, beta, out);
}